// Round 1
// baseline (729.017 us; speedup 1.0000x reference)
//
#include <hip/hip_runtime.h>
#include <math.h>

#define NB 128
#define NT 1000
#define DV 256
#define DQ 256
#define KSEL 6
#define TT 16

__device__ __forceinline__ float gelu_exact(float x) {
    return 0.5f * x * (1.0f + erff(x * 0.70710678118654752f));
}

__device__ __forceinline__ float block_sum256(float v, float* red) {
    #pragma unroll
    for (int o = 32; o; o >>= 1) v += __shfl_down(v, o, 64);
    int lane = threadIdx.x & 63, w = threadIdx.x >> 6;
    __syncthreads();
    if (lane == 0) red[w] = v;
    __syncthreads();
    return red[0] + red[1] + red[2] + red[3];
}

// ---------------- Kernel A: per-batch small MLPs ----------------
// mu_q = LN(gelu(q@mu_w1+b1)@mu_w2+b2); sigma = sigmoid(gelu(q@sg_w1+b1)@sg_w2+b2)*2+0.1
// qproj = q @ sel_w1[256:512,:] + sel_b1
__global__ __launch_bounds__(256) void prep_kernel(
    const float* __restrict__ q,
    const float* __restrict__ mu_w1, const float* __restrict__ mu_b1,
    const float* __restrict__ mu_w2, const float* __restrict__ mu_b2,
    const float* __restrict__ mu_g,  const float* __restrict__ mu_bb,
    const float* __restrict__ sg_w1, const float* __restrict__ sg_b1,
    const float* __restrict__ sg_w2, const float* __restrict__ sg_b2,
    const float* __restrict__ sel_w1, const float* __restrict__ sel_b1,
    float* __restrict__ mu_out, float* __restrict__ sig_out, float* __restrict__ qproj)
{
    __shared__ float qs[DQ];
    __shared__ float h1[2 * DV];
    __shared__ float red[4];
    int b = blockIdx.x, j = threadIdx.x;
    qs[j] = q[b * DQ + j];
    __syncthreads();

    // mu layer 1 (512 outputs, 2 per thread)
    for (int r = 0; r < 2; r++) {
        int jj = j + r * 256;
        float acc = mu_b1[jj];
        for (int i = 0; i < DQ; i++) acc = fmaf(qs[i], mu_w1[i * 512 + jj], acc);
        h1[jj] = gelu_exact(acc);
    }
    __syncthreads();

    // mu layer 2 + LayerNorm
    float acc = mu_b2[j];
    for (int i = 0; i < 512; i++) acc = fmaf(h1[i], mu_w2[i * DV + j], acc);
    float mean = block_sum256(acc, red) * (1.0f / 256.0f);
    float c = acc - mean;
    float var = block_sum256(c * c, red) * (1.0f / 256.0f);
    mu_out[b * DV + j] = c * rsqrtf(var + 1e-5f) * mu_g[j] + mu_bb[j];
    __syncthreads();   // before reusing h1

    // sigma layer 1
    acc = sg_b1[j];
    for (int i = 0; i < DQ; i++) acc = fmaf(qs[i], sg_w1[i * DV + j], acc);
    h1[j] = gelu_exact(acc);
    __syncthreads();

    // sigma layer 2
    acc = sg_b2[j];
    for (int i = 0; i < DV; i++) acc = fmaf(h1[i], sg_w2[i * DV + j], acc);
    sig_out[b * DV + j] = 2.0f / (1.0f + expf(-acc)) + 0.1f;

    // qproj (query part of sel layer 1)
    acc = sel_b1[j];
    for (int i = 0; i < DQ; i++) acc = fmaf(qs[i], sel_w1[(256 + i) * DV + j], acc);
    qproj[b * DV + j] = acc;
}

// ---------------- Kernel B: x = vf + pos; dist; rel (the big GEMM) ----------------
__global__ __launch_bounds__(256) void main_kernel(
    const float* __restrict__ vf, const float* __restrict__ pos,
    const float* __restrict__ mu_q, const float* __restrict__ sigma,
    const float* __restrict__ w1x, const float* __restrict__ w2,
    const float* __restrict__ sel_b2p, const float* __restrict__ qproj,
    float* __restrict__ x_out, float* __restrict__ dist_out, float* __restrict__ rel_out)
{
    __shared__ float xs[TT * DV];     // 16 KB
    __shared__ float red[TT][8];
    int b = blockIdx.y;
    int t0 = blockIdx.x * TT;
    int j = threadIdx.x;

    float mu  = mu_q[b * DV + j];
    float isg = 1.0f / (sigma[b * DV + j] + 1e-8f);

    float dpart[TT];
    #pragma unroll
    for (int tt = 0; tt < TT; tt++) {
        int t = t0 + tt;
        float v = 0.0f;
        if (t < NT) {
            v = vf[((long)b * NT + t) * DV + j] + pos[t * DV + j];
            x_out[((long)b * NT + t) * DV + j] = v;
        }
        xs[tt * DV + j] = v;
        float c = v - mu;
        dpart[tt] = c * c * isg;
    }
    __syncthreads();

    float h[TT];
    float qp = qproj[b * DV + j];
    #pragma unroll
    for (int tt = 0; tt < TT; tt++) h[tt] = qp;

    const float4* xs4 = (const float4*)xs;
    for (int i = 0; i < DV; i += 4) {
        float w0 = w1x[(i + 0) * DV + j];
        float w1 = w1x[(i + 1) * DV + j];
        float w2v = w1x[(i + 2) * DV + j];
        float w3 = w1x[(i + 3) * DV + j];
        #pragma unroll
        for (int tt = 0; tt < TT; tt++) {
            float4 xv = xs4[tt * (DV / 4) + (i >> 2)];
            h[tt] = fmaf(xv.x, w0, fmaf(xv.y, w1, fmaf(xv.z, w2v, fmaf(xv.w, w3, h[tt]))));
        }
    }

    float w2j = w2[j];
    float sb2 = sel_b2p[0];
    int lane = j & 63, wid = j >> 6;
    #pragma unroll
    for (int tt = 0; tt < TT; tt++) {
        float rp = gelu_exact(h[tt]) * w2j;
        float dp = dpart[tt];
        #pragma unroll
        for (int o = 32; o; o >>= 1) {
            rp += __shfl_down(rp, o, 64);
            dp += __shfl_down(dp, o, 64);
        }
        if (lane == 0) { red[tt][wid * 2] = dp; red[tt][wid * 2 + 1] = rp; }
    }
    __syncthreads();
    if (j < TT) {
        int t = t0 + j;
        if (t < NT) {
            float d = red[j][0] + red[j][2] + red[j][4] + red[j][6];
            float r = red[j][1] + red[j][3] + red[j][5] + red[j][7];
            dist_out[b * NT + t] = fmaxf(d, 1e-8f);
            rel_out[b * NT + t]  = r + sb2;
        }
    }
}

// ---------------- Kernel C: median, comb, top-12, diversify, gather ----------------
__global__ __launch_bounds__(256) void select_kernel(
    const float* __restrict__ dist, const float* __restrict__ rel,
    const float* __restrict__ x, float* __restrict__ rep_out, float* __restrict__ idx_out)
{
    __shared__ float sv[1024];
    __shared__ float comb[1024];
    __shared__ float bval[256];
    __shared__ int   bidx[256];
    __shared__ int   cand[12];
    __shared__ int   sel[KSEL];
    int b = blockIdx.x, tid = threadIdx.x;

    for (int t = tid; t < 1024; t += 256) sv[t] = (t < NT) ? dist[b * NT + t] : INFINITY;
    __syncthreads();

    // bitonic sort ascending over 1024
    for (int k = 2; k <= 1024; k <<= 1) {
        for (int jj = k >> 1; jj > 0; jj >>= 1) {
            for (int idx2 = tid; idx2 < 1024; idx2 += 256) {
                int ixj = idx2 ^ jj;
                if (ixj > idx2) {
                    float a = sv[idx2], bb = sv[ixj];
                    bool up = ((idx2 & k) == 0);
                    if ((a > bb) == up) { sv[idx2] = bb; sv[ixj] = a; }
                }
            }
            __syncthreads();
        }
    }
    float med = sv[499];   // torch lower-middle median, (T-1)//2

    for (int t = tid; t < 1024; t += 256)
        comb[t] = (t < NT) ? (-fabsf(dist[b * NT + t] - med) + 0.5f * rel[b * NT + t]) : -INFINITY;
    __syncthreads();

    // iterative argmax top-12 (lax.top_k tie-break: lower index first)
    for (int it = 0; it < 12; it++) {
        float best = -INFINITY; int bi = 1 << 30;
        for (int t = tid; t < 1024; t += 256) {
            float v = comb[t];
            if (v > best) { best = v; bi = t; }
        }
        bval[tid] = best; bidx[tid] = bi;
        __syncthreads();
        for (int s = 128; s > 0; s >>= 1) {
            if (tid < s) {
                float ov = bval[tid + s]; int oi = bidx[tid + s];
                if (ov > bval[tid] || (ov == bval[tid] && oi < bidx[tid])) {
                    bval[tid] = ov; bidx[tid] = oi;
                }
            }
            __syncthreads();
        }
        if (tid == 0) { cand[it] = bidx[0]; comb[bidx[0]] = -INFINITY; }
        __syncthreads();
    }

    // serial greedy farthest-point diversification (matches _diversify exactly)
    if (tid == 0) {
        int cs[12];
        for (int m = 0; m < 12; m++) cs[m] = cand[m];
        for (int a = 1; a < 12; a++) {            // insertion sort ascending
            int key = cs[a]; int bb = a - 1;
            while (bb >= 0 && cs[bb] > key) { cs[bb + 1] = cs[bb]; bb--; }
            cs[bb + 1] = key;
        }
        int md[12]; bool rem[12];
        for (int m = 0; m < 12; m++) { md[m] = abs(cs[m] - cs[0]); rem[m] = (m != 0); }
        sel[0] = cs[0];
        for (int st = 1; st < KSEL; st++) {
            int bestv = -2, bm = 0;
            for (int m = 0; m < 12; m++) {
                int sc = rem[m] ? md[m] : -1;
                if (sc > bestv) { bestv = sc; bm = m; }  // strict > = first occurrence
            }
            int s = cs[bm]; rem[bm] = false;
            for (int m = 0; m < 12; m++) { int d2 = abs(cs[m] - s); if (d2 < md[m]) md[m] = d2; }
            sel[st] = s;
        }
        for (int k2 = 0; k2 < KSEL; k2++) {
            int v = sel[k2];
            v = v < 0 ? 0 : (v > NT - 1 ? NT - 1 : v);
            sel[k2] = v;
            idx_out[b * KSEL + k2] = (float)v;
        }
    }
    __syncthreads();
    for (int k2 = 0; k2 < KSEL; k2++)
        rep_out[((long)b * KSEL + k2) * DV + tid] = x[((long)b * NT + sel[k2]) * DV + tid];
}

extern "C" void kernel_launch(void* const* d_in, const int* in_sizes, int n_in,
                              void* d_out, int out_size, void* d_ws, size_t ws_size,
                              hipStream_t stream) {
    const float* vf     = (const float*)d_in[0];
    const float* q      = (const float*)d_in[1];
    const float* pos    = (const float*)d_in[2];
    const float* mu_w1  = (const float*)d_in[3];
    const float* mu_b1  = (const float*)d_in[4];
    const float* mu_w2  = (const float*)d_in[5];
    const float* mu_b2  = (const float*)d_in[6];
    const float* mu_g   = (const float*)d_in[7];
    const float* mu_bb  = (const float*)d_in[8];
    const float* sg_w1  = (const float*)d_in[9];
    const float* sg_b1  = (const float*)d_in[10];
    const float* sg_w2  = (const float*)d_in[11];
    const float* sg_b2  = (const float*)d_in[12];
    const float* sel_w1 = (const float*)d_in[13];
    const float* sel_b1 = (const float*)d_in[14];
    const float* sel_w2 = (const float*)d_in[15];
    const float* sel_b2 = (const float*)d_in[16];

    float* o = (float*)d_out;
    // output layout (floats): rep | idx | dist | mu_q | sigma | x
    float* rep_o  = o;
    float* idx_o  = o + 196608;
    float* dist_o = o + 197376;
    float* mu_o   = o + 325376;
    float* sig_o  = o + 358144;
    float* x_o    = o + 390912;

    float* qproj = (float*)d_ws;                 // [128*256]
    float* rel   = (float*)d_ws + NB * DQ;       // [128*1000]

    prep_kernel<<<NB, 256, 0, stream>>>(q, mu_w1, mu_b1, mu_w2, mu_b2, mu_g, mu_bb,
                                        sg_w1, sg_b1, sg_w2, sg_b2, sel_w1, sel_b1,
                                        mu_o, sig_o, qproj);

    dim3 grid((NT + TT - 1) / TT, NB);
    main_kernel<<<grid, 256, 0, stream>>>(vf, pos, mu_o, sig_o, sel_w1, sel_w2, sel_b2,
                                          qproj, x_o, dist_o, rel);

    select_kernel<<<NB, 256, 0, stream>>>(dist_o, rel, x_o, rep_o, idx_o);
}

// Round 2
// 650.993 us; speedup vs baseline: 1.1199x; 1.1199x over previous
//
#include <hip/hip_runtime.h>
#include <math.h>

#define NB 128
#define NT 1000
#define DV 256
#define DQ 256
#define KSEL 6
#define TT 32

__device__ __forceinline__ float gelu_exact(float x) {
    return 0.5f * x * (1.0f + erff(x * 0.70710678118654752f));
}

__device__ __forceinline__ float block_sum256(float v, float* red) {
    #pragma unroll
    for (int o = 32; o; o >>= 1) v += __shfl_down(v, o, 64);
    int lane = threadIdx.x & 63, w = threadIdx.x >> 6;
    __syncthreads();
    if (lane == 0) red[w] = v;
    __syncthreads();
    return red[0] + red[1] + red[2] + red[3];
}

// ---------------- Kernel A: per-batch small MLPs ----------------
__global__ __launch_bounds__(256) void prep_kernel(
    const float* __restrict__ q,
    const float* __restrict__ mu_w1, const float* __restrict__ mu_b1,
    const float* __restrict__ mu_w2, const float* __restrict__ mu_b2,
    const float* __restrict__ mu_g,  const float* __restrict__ mu_bb,
    const float* __restrict__ sg_w1, const float* __restrict__ sg_b1,
    const float* __restrict__ sg_w2, const float* __restrict__ sg_b2,
    const float* __restrict__ sel_w1, const float* __restrict__ sel_b1,
    float* __restrict__ mu_out, float* __restrict__ sig_out, float* __restrict__ qproj)
{
    __shared__ float qs[DQ];
    __shared__ float h1[2 * DV];
    __shared__ float red[4];
    int b = blockIdx.x, j = threadIdx.x;
    qs[j] = q[b * DQ + j];
    __syncthreads();

    for (int r = 0; r < 2; r++) {
        int jj = j + r * 256;
        float acc = mu_b1[jj];
        for (int i = 0; i < DQ; i++) acc = fmaf(qs[i], mu_w1[i * 512 + jj], acc);
        h1[jj] = gelu_exact(acc);
    }
    __syncthreads();

    float acc = mu_b2[j];
    for (int i = 0; i < 512; i++) acc = fmaf(h1[i], mu_w2[i * DV + j], acc);
    float mean = block_sum256(acc, red) * (1.0f / 256.0f);
    float c = acc - mean;
    float var = block_sum256(c * c, red) * (1.0f / 256.0f);
    mu_out[b * DV + j] = c * rsqrtf(var + 1e-5f) * mu_g[j] + mu_bb[j];
    __syncthreads();

    acc = sg_b1[j];
    for (int i = 0; i < DQ; i++) acc = fmaf(qs[i], sg_w1[i * DV + j], acc);
    h1[j] = gelu_exact(acc);
    __syncthreads();

    acc = sg_b2[j];
    for (int i = 0; i < DV; i++) acc = fmaf(h1[i], sg_w2[i * DV + j], acc);
    sig_out[b * DV + j] = 2.0f / (1.0f + expf(-acc)) + 0.1f;

    acc = sel_b1[j];
    for (int i = 0; i < DQ; i++) acc = fmaf(qs[i], sel_w1[(256 + i) * DV + j], acc);
    qproj[b * DV + j] = acc;
}

// ---------------- Kernel B: x = vf + pos; dist; rel GEMM (register-tiled) ----------------
// Block: 256 threads, covers TT=32 t's x 256 j.
// Staging map: thread tid = column j, 32 t's. GEMM map: jg = tid&63 (j0=4*jg), tg = tid>>6 (8 t's).
__global__ __launch_bounds__(256, 3) void main_kernel(
    const float* __restrict__ vf, const float* __restrict__ pos,
    const float* __restrict__ mu_q, const float* __restrict__ sigma,
    const float* __restrict__ w1x, const float* __restrict__ w2,
    const float* __restrict__ sel_b2p, const float* __restrict__ qproj,
    float* __restrict__ x_out, float* __restrict__ dist_out, float* __restrict__ rel_out)
{
    __shared__ float xs[TT * DV];      // 32 KB, xs[tt*256 + i]
    __shared__ float ws[16 * DV];      // 16 KB, staged w chunk ws[ii*256 + j]
    __shared__ float redd[TT * 4];

    int b = blockIdx.y;
    int t0 = blockIdx.x * TT;
    int tid = threadIdx.x;
    int j = tid;
    int lane = tid & 63, wv_id = tid >> 6;

    float mu  = mu_q[b * DV + j];
    float isg = 1.0f / (sigma[b * DV + j] + 1e-8f);

    // ---- staging: x = vf + pos, write x_out, fill LDS, per-thread dist partials ----
    float dpart[TT];
    #pragma unroll
    for (int tt = 0; tt < TT; tt++) {
        int t = t0 + tt;
        float v = 0.0f;
        if (t < NT) {
            v = vf[((long)b * NT + t) * DV + j] + pos[t * DV + j];
            x_out[((long)b * NT + t) * DV + j] = v;
        }
        xs[tt * DV + j] = v;
        float c = v - mu;
        dpart[tt] = c * c * isg;
    }

    // ---- dist reduction (sum over 256 j) ----
    #pragma unroll
    for (int tt = 0; tt < TT; tt++) {
        float dp = dpart[tt];
        #pragma unroll
        for (int o = 32; o; o >>= 1) dp += __shfl_down(dp, o, 64);
        if (lane == 0) redd[tt * 4 + wv_id] = dp;
    }
    __syncthreads();
    if (tid < TT) {
        int t = t0 + tid;
        if (t < NT) {
            float d = redd[tid * 4] + redd[tid * 4 + 1] + redd[tid * 4 + 2] + redd[tid * 4 + 3];
            dist_out[b * NT + t] = fmaxf(d, 1e-8f);
        }
    }

    // ---- GEMM: h[t][j] = qproj[j] + sum_i x[t][i] * w1x[i][j] ----
    int jg = tid & 63, tg = tid >> 6;
    float acc[8][4];
    float4 q4 = ((const float4*)(qproj + (long)b * DV))[jg];
    #pragma unroll
    for (int tt = 0; tt < 8; tt++) {
        acc[tt][0] = q4.x; acc[tt][1] = q4.y; acc[tt][2] = q4.z; acc[tt][3] = q4.w;
    }

    const float4* xs4 = (const float4*)xs;
    const float4* ws4 = (const float4*)ws;
    float4* wsw = (float4*)ws;

    for (int c = 0; c < 16; c++) {
        __syncthreads();   // previous chunk fully consumed
        // stage 16 rows of w1x into LDS (linear copy, coalesced)
        const float4* wsrc = (const float4*)(w1x + c * 16 * DV);
        float4 tmp0 = wsrc[0 * 256 + tid];
        float4 tmp1 = wsrc[1 * 256 + tid];
        float4 tmp2 = wsrc[2 * 256 + tid];
        float4 tmp3 = wsrc[3 * 256 + tid];
        wsw[0 * 256 + tid] = tmp0;
        wsw[1 * 256 + tid] = tmp1;
        wsw[2 * 256 + tid] = tmp2;
        wsw[3 * 256 + tid] = tmp3;
        __syncthreads();

        #pragma unroll
        for (int g = 0; g < 4; g++) {
            int ib = c * 16 + g * 4;           // base i of this 4-wide group
            float4 wf[4];
            #pragma unroll
            for (int di = 0; di < 4; di++) wf[di] = ws4[(g * 4 + di) * 64 + jg];
            #pragma unroll
            for (int tt = 0; tt < 8; tt++) {
                float4 xv = xs4[(tg * 8 + tt) * 64 + (ib >> 2)];   // wave-broadcast
                acc[tt][0] = fmaf(xv.x, wf[0].x, acc[tt][0]);
                acc[tt][1] = fmaf(xv.x, wf[0].y, acc[tt][1]);
                acc[tt][2] = fmaf(xv.x, wf[0].z, acc[tt][2]);
                acc[tt][3] = fmaf(xv.x, wf[0].w, acc[tt][3]);
                acc[tt][0] = fmaf(xv.y, wf[1].x, acc[tt][0]);
                acc[tt][1] = fmaf(xv.y, wf[1].y, acc[tt][1]);
                acc[tt][2] = fmaf(xv.y, wf[1].z, acc[tt][2]);
                acc[tt][3] = fmaf(xv.y, wf[1].w, acc[tt][3]);
                acc[tt][0] = fmaf(xv.z, wf[2].x, acc[tt][0]);
                acc[tt][1] = fmaf(xv.z, wf[2].y, acc[tt][1]);
                acc[tt][2] = fmaf(xv.z, wf[2].z, acc[tt][2]);
                acc[tt][3] = fmaf(xv.z, wf[2].w, acc[tt][3]);
                acc[tt][0] = fmaf(xv.w, wf[3].x, acc[tt][0]);
                acc[tt][1] = fmaf(xv.w, wf[3].y, acc[tt][1]);
                acc[tt][2] = fmaf(xv.w, wf[3].z, acc[tt][2]);
                acc[tt][3] = fmaf(xv.w, wf[3].w, acc[tt][3]);
            }
        }
    }

    // ---- epilogue: rel[t] = sum_j gelu(h[t][j]) * w2[j] + b2 (wave-local reduce) ----
    float4 w24 = ((const float4*)w2)[jg];
    float sb2 = sel_b2p[0];
    #pragma unroll
    for (int tt = 0; tt < 8; tt++) {
        float r = gelu_exact(acc[tt][0]) * w24.x
                + gelu_exact(acc[tt][1]) * w24.y
                + gelu_exact(acc[tt][2]) * w24.z
                + gelu_exact(acc[tt][3]) * w24.w;
        #pragma unroll
        for (int o = 32; o; o >>= 1) r += __shfl_down(r, o, 64);
        if (lane == 0) {
            int t = t0 + tg * 8 + tt;
            if (t < NT) rel_out[b * NT + t] = r + sb2;
        }
    }
}

// ---------------- Kernel C: median, comb, top-12, diversify, gather ----------------
__global__ __launch_bounds__(256) void select_kernel(
    const float* __restrict__ dist, const float* __restrict__ rel,
    const float* __restrict__ x, float* __restrict__ rep_out, float* __restrict__ idx_out)
{
    __shared__ float sv[1024];
    __shared__ float comb[1024];
    __shared__ float bval[256];
    __shared__ int   bidx[256];
    __shared__ int   cand[12];
    __shared__ int   sel[KSEL];
    int b = blockIdx.x, tid = threadIdx.x;

    for (int t = tid; t < 1024; t += 256) sv[t] = (t < NT) ? dist[b * NT + t] : INFINITY;
    __syncthreads();

    for (int k = 2; k <= 1024; k <<= 1) {
        for (int jj = k >> 1; jj > 0; jj >>= 1) {
            for (int idx2 = tid; idx2 < 1024; idx2 += 256) {
                int ixj = idx2 ^ jj;
                if (ixj > idx2) {
                    float a = sv[idx2], bb = sv[ixj];
                    bool up = ((idx2 & k) == 0);
                    if ((a > bb) == up) { sv[idx2] = bb; sv[ixj] = a; }
                }
            }
            __syncthreads();
        }
    }
    float med = sv[499];

    for (int t = tid; t < 1024; t += 256)
        comb[t] = (t < NT) ? (-fabsf(dist[b * NT + t] - med) + 0.5f * rel[b * NT + t]) : -INFINITY;
    __syncthreads();

    for (int it = 0; it < 12; it++) {
        float best = -INFINITY; int bi = 1 << 30;
        for (int t = tid; t < 1024; t += 256) {
            float v = comb[t];
            if (v > best) { best = v; bi = t; }
        }
        bval[tid] = best; bidx[tid] = bi;
        __syncthreads();
        for (int s = 128; s > 0; s >>= 1) {
            if (tid < s) {
                float ov = bval[tid + s]; int oi = bidx[tid + s];
                if (ov > bval[tid] || (ov == bval[tid] && oi < bidx[tid])) {
                    bval[tid] = ov; bidx[tid] = oi;
                }
            }
            __syncthreads();
        }
        if (tid == 0) { cand[it] = bidx[0]; comb[bidx[0]] = -INFINITY; }
        __syncthreads();
    }

    if (tid == 0) {
        int cs[12];
        for (int m = 0; m < 12; m++) cs[m] = cand[m];
        for (int a = 1; a < 12; a++) {
            int key = cs[a]; int bb = a - 1;
            while (bb >= 0 && cs[bb] > key) { cs[bb + 1] = cs[bb]; bb--; }
            cs[bb + 1] = key;
        }
        int md[12]; bool rem[12];
        for (int m = 0; m < 12; m++) { md[m] = abs(cs[m] - cs[0]); rem[m] = (m != 0); }
        sel[0] = cs[0];
        for (int st = 1; st < KSEL; st++) {
            int bestv = -2, bm = 0;
            for (int m = 0; m < 12; m++) {
                int sc = rem[m] ? md[m] : -1;
                if (sc > bestv) { bestv = sc; bm = m; }
            }
            int s = cs[bm]; rem[bm] = false;
            for (int m = 0; m < 12; m++) { int d2 = abs(cs[m] - s); if (d2 < md[m]) md[m] = d2; }
            sel[st] = s;
        }
        for (int k2 = 0; k2 < KSEL; k2++) {
            int v = sel[k2];
            v = v < 0 ? 0 : (v > NT - 1 ? NT - 1 : v);
            sel[k2] = v;
            idx_out[b * KSEL + k2] = (float)v;
        }
    }
    __syncthreads();
    for (int k2 = 0; k2 < KSEL; k2++)
        rep_out[((long)b * KSEL + k2) * DV + tid] = x[((long)b * NT + sel[k2]) * DV + tid];
}

extern "C" void kernel_launch(void* const* d_in, const int* in_sizes, int n_in,
                              void* d_out, int out_size, void* d_ws, size_t ws_size,
                              hipStream_t stream) {
    const float* vf     = (const float*)d_in[0];
    const float* q      = (const float*)d_in[1];
    const float* pos    = (const float*)d_in[2];
    const float* mu_w1  = (const float*)d_in[3];
    const float* mu_b1  = (const float*)d_in[4];
    const float* mu_w2  = (const float*)d_in[5];
    const float* mu_b2  = (const float*)d_in[6];
    const float* mu_g   = (const float*)d_in[7];
    const float* mu_bb  = (const float*)d_in[8];
    const float* sg_w1  = (const float*)d_in[9];
    const float* sg_b1  = (const float*)d_in[10];
    const float* sg_w2  = (const float*)d_in[11];
    const float* sg_b2  = (const float*)d_in[12];
    const float* sel_w1 = (const float*)d_in[13];
    const float* sel_b1 = (const float*)d_in[14];
    const float* sel_w2 = (const float*)d_in[15];
    const float* sel_b2 = (const float*)d_in[16];

    float* o = (float*)d_out;
    float* rep_o  = o;
    float* idx_o  = o + 196608;
    float* dist_o = o + 197376;
    float* mu_o   = o + 325376;
    float* sig_o  = o + 358144;
    float* x_o    = o + 390912;

    float* qproj = (float*)d_ws;                 // [128*256]
    float* rel   = (float*)d_ws + NB * DQ;       // [128*1000]

    prep_kernel<<<NB, 256, 0, stream>>>(q, mu_w1, mu_b1, mu_w2, mu_b2, mu_g, mu_bb,
                                        sg_w1, sg_b1, sg_w2, sg_b2, sel_w1, sel_b1,
                                        mu_o, sig_o, qproj);

    dim3 grid((NT + TT - 1) / TT, NB);
    main_kernel<<<grid, 256, 0, stream>>>(vf, pos, mu_o, sig_o, sel_w1, sel_w2, sel_b2,
                                          qproj, x_o, dist_o, rel);

    select_kernel<<<NB, 256, 0, stream>>>(dist_o, rel, x_o, rep_o, idx_o);
}

// Round 3
// 475.819 us; speedup vs baseline: 1.5321x; 1.3682x over previous
//
#include <hip/hip_runtime.h>
#include <math.h>

#define NB 128
#define NT 1000
#define DV 256
#define DQ 256
#define KSEL 6
#define TT 32

typedef __attribute__((ext_vector_type(8))) short short8;
typedef __attribute__((ext_vector_type(4))) float float4v;

// swizzled bf16 hi/lo of sel_w1[0:256,:] in MFMA B-fragment order:
// [kc(8)][ntile(16)][lane(64)][r(8)], element = w[kc*32 + (lane>>4)*8 + r][ntile*16 + (lane&15)]
__device__ short g_whB[8 * 16 * 64 * 8];
__device__ short g_wlB[8 * 16 * 64 * 8];

__device__ __forceinline__ float gelu_exact(float x) {
    return 0.5f * x * (1.0f + erff(x * 0.70710678118654752f));
}
__device__ __forceinline__ unsigned short f2bf(float f) {
    unsigned u = __float_as_uint(f);
    return (unsigned short)((u + 0x7FFFu + ((u >> 16) & 1u)) >> 16);
}
__device__ __forceinline__ float bf2f(unsigned short h) {
    return __uint_as_float(((unsigned)h) << 16);
}

__device__ __forceinline__ float block_sum256(float v, float* red) {
    #pragma unroll
    for (int o = 32; o; o >>= 1) v += __shfl_down(v, o, 64);
    int lane = threadIdx.x & 63, w = threadIdx.x >> 6;
    __syncthreads();
    if (lane == 0) red[w] = v;
    __syncthreads();
    return red[0] + red[1] + red[2] + red[3];
}

// ---------------- weight swizzle: sel_w1 x-part -> bf16 hi/lo B-fragments ----------------
__global__ __launch_bounds__(64) void wswz_kernel(const float* __restrict__ sel_w1) {
    int blk = blockIdx.x;            // kc*16 + nt
    int kc = blk >> 4, nt = blk & 15;
    int lane = threadIdx.x;
    int q = lane >> 4, n = nt * 16 + (lane & 15);
    short8 hi, lo;
    #pragma unroll
    for (int r = 0; r < 8; r++) {
        float wv = sel_w1[(kc * 32 + q * 8 + r) * 256 + n];
        unsigned short h = f2bf(wv);
        hi[r] = (short)h;
        lo[r] = (short)f2bf(wv - bf2f(h));
    }
    ((short8*)g_whB)[blk * 64 + lane] = hi;
    ((short8*)g_wlB)[blk * 64 + lane] = lo;
}

// ---------------- Kernel A: per-batch small MLPs (ILP'd) ----------------
__global__ __launch_bounds__(256) void prep_kernel(
    const float* __restrict__ q,
    const float* __restrict__ mu_w1, const float* __restrict__ mu_b1,
    const float* __restrict__ mu_w2, const float* __restrict__ mu_b2,
    const float* __restrict__ mu_g,  const float* __restrict__ mu_bb,
    const float* __restrict__ sg_w1, const float* __restrict__ sg_b1,
    const float* __restrict__ sg_w2, const float* __restrict__ sg_b2,
    const float* __restrict__ sel_w1, const float* __restrict__ sel_b1,
    float* __restrict__ mu_out, float* __restrict__ sig_out, float* __restrict__ qproj)
{
    __shared__ float qs[DQ];
    __shared__ float h1[2 * DV];
    __shared__ float red[4];
    int b = blockIdx.x, j = threadIdx.x;
    qs[j] = q[b * DQ + j];
    __syncthreads();

    for (int r = 0; r < 2; r++) {
        int jj = j + r * 256;
        float a0 = 0.f, a1 = 0.f, a2 = 0.f, a3 = 0.f;
        #pragma unroll 8
        for (int i = 0; i < DQ; i += 4) {
            a0 = fmaf(qs[i + 0], mu_w1[(i + 0) * 512 + jj], a0);
            a1 = fmaf(qs[i + 1], mu_w1[(i + 1) * 512 + jj], a1);
            a2 = fmaf(qs[i + 2], mu_w1[(i + 2) * 512 + jj], a2);
            a3 = fmaf(qs[i + 3], mu_w1[(i + 3) * 512 + jj], a3);
        }
        h1[jj] = gelu_exact(mu_b1[jj] + ((a0 + a1) + (a2 + a3)));
    }
    __syncthreads();

    {
        float a0 = 0.f, a1 = 0.f, a2 = 0.f, a3 = 0.f;
        #pragma unroll 8
        for (int i = 0; i < 512; i += 4) {
            a0 = fmaf(h1[i + 0], mu_w2[(i + 0) * DV + j], a0);
            a1 = fmaf(h1[i + 1], mu_w2[(i + 1) * DV + j], a1);
            a2 = fmaf(h1[i + 2], mu_w2[(i + 2) * DV + j], a2);
            a3 = fmaf(h1[i + 3], mu_w2[(i + 3) * DV + j], a3);
        }
        float acc = mu_b2[j] + ((a0 + a1) + (a2 + a3));
        float mean = block_sum256(acc, red) * (1.0f / 256.0f);
        float c = acc - mean;
        float var = block_sum256(c * c, red) * (1.0f / 256.0f);
        mu_out[b * DV + j] = c * rsqrtf(var + 1e-5f) * mu_g[j] + mu_bb[j];
    }
    __syncthreads();

    {
        float a0 = 0.f, a1 = 0.f, a2 = 0.f, a3 = 0.f;
        #pragma unroll 8
        for (int i = 0; i < DQ; i += 4) {
            a0 = fmaf(qs[i + 0], sg_w1[(i + 0) * DV + j], a0);
            a1 = fmaf(qs[i + 1], sg_w1[(i + 1) * DV + j], a1);
            a2 = fmaf(qs[i + 2], sg_w1[(i + 2) * DV + j], a2);
            a3 = fmaf(qs[i + 3], sg_w1[(i + 3) * DV + j], a3);
        }
        h1[j] = gelu_exact(sg_b1[j] + ((a0 + a1) + (a2 + a3)));
    }
    __syncthreads();

    {
        float a0 = 0.f, a1 = 0.f, a2 = 0.f, a3 = 0.f;
        #pragma unroll 8
        for (int i = 0; i < DV; i += 4) {
            a0 = fmaf(h1[i + 0], sg_w2[(i + 0) * DV + j], a0);
            a1 = fmaf(h1[i + 1], sg_w2[(i + 1) * DV + j], a1);
            a2 = fmaf(h1[i + 2], sg_w2[(i + 2) * DV + j], a2);
            a3 = fmaf(h1[i + 3], sg_w2[(i + 3) * DV + j], a3);
        }
        float acc = sg_b2[j] + ((a0 + a1) + (a2 + a3));
        sig_out[b * DV + j] = 2.0f / (1.0f + expf(-acc)) + 0.1f;
    }

    {
        float a0 = 0.f, a1 = 0.f, a2 = 0.f, a3 = 0.f;
        #pragma unroll 8
        for (int i = 0; i < DQ; i += 4) {
            a0 = fmaf(qs[i + 0], sel_w1[(256 + i + 0) * DV + j], a0);
            a1 = fmaf(qs[i + 1], sel_w1[(256 + i + 1) * DV + j], a1);
            a2 = fmaf(qs[i + 2], sel_w1[(256 + i + 2) * DV + j], a2);
            a3 = fmaf(qs[i + 3], sel_w1[(256 + i + 3) * DV + j], a3);
        }
        qproj[b * DV + j] = sel_b1[j] + ((a0 + a1) + (a2 + a3));
    }
}

// ---------------- Kernel B: x=vf+pos, dist, rel via bf16-split MFMA ----------------
__global__ __launch_bounds__(256) void main_kernel(
    const float* __restrict__ vf, const float* __restrict__ pos,
    const float* __restrict__ mu_q, const float* __restrict__ sigma,
    const float* __restrict__ w2, const float* __restrict__ sel_b2p,
    const float* __restrict__ qproj,
    float* __restrict__ x_out, float* __restrict__ dist_out, float* __restrict__ rel_out)
{
    __shared__ __align__(16) short xh[TT][264];   // +8 pad: even bank spread for b128 frag reads
    __shared__ __align__(16) short xl[TT][264];
    __shared__ float redd[TT * 4];
    __shared__ float relp[TT][4];

    int b = blockIdx.y;
    int t0 = blockIdx.x * TT;
    int tid = threadIdx.x;
    int lane = tid & 63, wv = tid >> 6;

    float mu  = mu_q[b * DV + tid];
    float isg = 1.0f / (sigma[b * DV + tid] + 1e-8f);

    // staging: x = vf+pos -> x_out, bf16 hi/lo -> LDS, dist partial reduce (same order as R2)
    for (int tt = 0; tt < TT; tt++) {
        int t = t0 + tt;
        float v = 0.0f;
        if (t < NT) {
            v = vf[((long)b * NT + t) * DV + tid] + pos[t * DV + tid];
            x_out[((long)b * NT + t) * DV + tid] = v;
        }
        unsigned short h = f2bf(v);
        xh[tt][tid] = (short)h;
        xl[tt][tid] = (short)f2bf(v - bf2f(h));
        float c = v - mu;
        float dp = c * c * isg;
        #pragma unroll
        for (int o = 32; o; o >>= 1) dp += __shfl_down(dp, o, 64);
        if (lane == 0) redd[tt * 4 + wv] = dp;
    }
    __syncthreads();
    if (tid < TT) {
        int t = t0 + tid;
        if (t < NT)
            dist_out[b * NT + t] =
                fmaxf(redd[tid * 4] + redd[tid * 4 + 1] + redd[tid * 4 + 2] + redd[tid * 4 + 3], 1e-8f);
    }

    // MFMA: h[t][j] = qproj[j] + sum_i x[t][i]*w[i][j], 3-product bf16 split
    int col = lane & 15, quad = lane >> 4;
    float4v acc[2][4];
    #pragma unroll
    for (int m = 0; m < 2; m++)
        #pragma unroll
        for (int n = 0; n < 4; n++)
            #pragma unroll
            for (int r = 0; r < 4; r++) acc[m][n][r] = 0.0f;

    const short8* whp = (const short8*)g_whB;
    const short8* wlp = (const short8*)g_wlB;

    #pragma unroll 2
    for (int kc = 0; kc < 8; kc++) {
        short8 ah[2], al[2], bh[4], bl[4];
        #pragma unroll
        for (int m = 0; m < 2; m++) {
            ah[m] = *(const short8*)&xh[m * 16 + col][kc * 32 + quad * 8];
            al[m] = *(const short8*)&xl[m * 16 + col][kc * 32 + quad * 8];
        }
        #pragma unroll
        for (int n = 0; n < 4; n++) {
            int gnt = wv * 4 + n;
            bh[n] = whp[(kc * 16 + gnt) * 64 + lane];
            bl[n] = wlp[(kc * 16 + gnt) * 64 + lane];
        }
        #pragma unroll
        for (int m = 0; m < 2; m++)
            #pragma unroll
            for (int n = 0; n < 4; n++) {
                acc[m][n] = __builtin_amdgcn_mfma_f32_16x16x32_bf16(ah[m], bh[n], acc[m][n], 0, 0, 0);
                acc[m][n] = __builtin_amdgcn_mfma_f32_16x16x32_bf16(ah[m], bl[n], acc[m][n], 0, 0, 0);
                acc[m][n] = __builtin_amdgcn_mfma_f32_16x16x32_bf16(al[m], bh[n], acc[m][n], 0, 0, 0);
            }
    }

    // epilogue: rel[t] = sum_j gelu(h)*w2[j] + b2
    float w2v[4], qpv[4];
    #pragma unroll
    for (int n = 0; n < 4; n++) {
        int jj = (wv * 4 + n) * 16 + col;
        w2v[n] = w2[jj];
        qpv[n] = qproj[b * DV + jj];
    }
    #pragma unroll
    for (int m = 0; m < 2; m++)
        #pragma unroll
        for (int r = 0; r < 4; r++) {
            float s = gelu_exact(acc[m][0][r] + qpv[0]) * w2v[0]
                    + gelu_exact(acc[m][1][r] + qpv[1]) * w2v[1]
                    + gelu_exact(acc[m][2][r] + qpv[2]) * w2v[2]
                    + gelu_exact(acc[m][3][r] + qpv[3]) * w2v[3];
            #pragma unroll
            for (int o = 8; o; o >>= 1) s += __shfl_down(s, o, 16);
            if (col == 0) relp[m * 16 + quad * 4 + r][wv] = s;
        }
    __syncthreads();
    if (tid < TT) {
        int t = t0 + tid;
        if (t < NT)
            rel_out[b * NT + t] = relp[tid][0] + relp[tid][1] + relp[tid][2] + relp[tid][3] + sel_b2p[0];
    }
}

// ---------------- Kernel C: exact median (radix bisect), comb, top-12, diversify, gather ----------------
__global__ __launch_bounds__(256) void select_kernel(
    const float* __restrict__ dist, const float* __restrict__ rel,
    const float* __restrict__ x, float* __restrict__ rep_out, float* __restrict__ idx_out)
{
    __shared__ int sel_s[KSEL];
    int b = blockIdx.x, tid = threadIdx.x;

    if (tid < 64) {
        int lane = tid;
        float dv[16], cv[16];
        unsigned key[16];
        #pragma unroll
        for (int s = 0; s < 16; s++) {
            int t = s * 64 + lane;
            float d = (t < NT) ? dist[b * NT + t] : __builtin_inff();
            dv[s] = d;
            unsigned u = __float_as_uint(d);
            key[s] = (u & 0x80000000u) ? ~u : (u | 0x80000000u);
        }
        // exact rank-499 order statistic via 32-step bit bisection (no barriers)
        unsigned prefix = 0u;
        for (int bit = 31; bit >= 0; bit--) {
            unsigned mid = prefix | (1u << bit);
            int c = 0;
            #pragma unroll
            for (int s = 0; s < 16; s++) c += (key[s] < mid) ? 1 : 0;
            #pragma unroll
            for (int o = 1; o < 64; o <<= 1) c += __shfl_xor(c, o, 64);
            if (c <= 499) prefix = mid;
        }
        unsigned mu2 = (prefix & 0x80000000u) ? (prefix & 0x7FFFFFFFu) : ~prefix;
        float med = __uint_as_float(mu2);

        #pragma unroll
        for (int s = 0; s < 16; s++) {
            int t = s * 64 + lane;
            cv[s] = (t < NT) ? (-fabsf(dv[s] - med) + 0.5f * rel[b * NT + t]) : -__builtin_inff();
        }

        int cand[12];
        for (int it = 0; it < 12; it++) {
            float best = -__builtin_inff(); int bi = 1 << 30;
            #pragma unroll
            for (int s = 0; s < 16; s++) {
                if (cv[s] > best) { best = cv[s]; bi = s * 64 + lane; }
            }
            #pragma unroll
            for (int o = 1; o < 64; o <<= 1) {
                float ov = __shfl_xor(best, o, 64);
                int   oi = __shfl_xor(bi, o, 64);
                if (ov > best || (ov == best && oi < bi)) { best = ov; bi = oi; }
            }
            cand[it] = bi;
            #pragma unroll
            for (int s = 0; s < 16; s++) if (s * 64 + lane == bi) cv[s] = -__builtin_inff();
        }

        if (lane == 0) {
            int cs[12];
            for (int m = 0; m < 12; m++) cs[m] = cand[m];
            for (int a = 1; a < 12; a++) {
                int keyv = cs[a]; int bb = a - 1;
                while (bb >= 0 && cs[bb] > keyv) { cs[bb + 1] = cs[bb]; bb--; }
                cs[bb + 1] = keyv;
            }
            int md[12]; bool rem[12];
            for (int m = 0; m < 12; m++) { md[m] = abs(cs[m] - cs[0]); rem[m] = (m != 0); }
            int selv[KSEL];
            selv[0] = cs[0];
            for (int st = 1; st < KSEL; st++) {
                int bestv = -2, bm = 0;
                for (int m = 0; m < 12; m++) {
                    int sc = rem[m] ? md[m] : -1;
                    if (sc > bestv) { bestv = sc; bm = m; }
                }
                int s = cs[bm]; rem[bm] = false;
                for (int m = 0; m < 12; m++) { int d2 = abs(cs[m] - s); if (d2 < md[m]) md[m] = d2; }
                selv[st] = s;
            }
            for (int k2 = 0; k2 < KSEL; k2++) {
                int v = selv[k2];
                v = v < 0 ? 0 : (v > NT - 1 ? NT - 1 : v);
                sel_s[k2] = v;
                idx_out[b * KSEL + k2] = (float)v;
            }
        }
    }
    __syncthreads();
    #pragma unroll
    for (int k2 = 0; k2 < KSEL; k2++)
        rep_out[((long)b * KSEL + k2) * DV + tid] = x[((long)b * NT + sel_s[k2]) * DV + tid];
}

extern "C" void kernel_launch(void* const* d_in, const int* in_sizes, int n_in,
                              void* d_out, int out_size, void* d_ws, size_t ws_size,
                              hipStream_t stream) {
    const float* vf     = (const float*)d_in[0];
    const float* q      = (const float*)d_in[1];
    const float* pos    = (const float*)d_in[2];
    const float* mu_w1  = (const float*)d_in[3];
    const float* mu_b1  = (const float*)d_in[4];
    const float* mu_w2  = (const float*)d_in[5];
    const float* mu_b2  = (const float*)d_in[6];
    const float* mu_g   = (const float*)d_in[7];
    const float* mu_bb  = (const float*)d_in[8];
    const float* sg_w1  = (const float*)d_in[9];
    const float* sg_b1  = (const float*)d_in[10];
    const float* sg_w2  = (const float*)d_in[11];
    const float* sg_b2  = (const float*)d_in[12];
    const float* sel_w1 = (const float*)d_in[13];
    const float* sel_b1 = (const float*)d_in[14];
    const float* sel_w2 = (const float*)d_in[15];
    const float* sel_b2 = (const float*)d_in[16];

    float* o = (float*)d_out;
    float* rep_o  = o;
    float* idx_o  = o + 196608;
    float* dist_o = o + 197376;
    float* mu_o   = o + 325376;
    float* sig_o  = o + 358144;
    float* x_o    = o + 390912;

    float* qproj = (float*)d_ws;                 // [128*256]
    float* rel   = (float*)d_ws + NB * DQ;       // [128*1000]

    wswz_kernel<<<128, 64, 0, stream>>>(sel_w1);
    prep_kernel<<<NB, 256, 0, stream>>>(q, mu_w1, mu_b1, mu_w2, mu_b2, mu_g, mu_bb,
                                        sg_w1, sg_b1, sg_w2, sg_b2, sel_w1, sel_b1,
                                        mu_o, sig_o, qproj);

    dim3 grid((NT + TT - 1) / TT, NB);
    main_kernel<<<grid, 256, 0, stream>>>(vf, pos, mu_o, sig_o, sel_w2, sel_b2,
                                          qproj, x_o, dist_o, rel);

    select_kernel<<<NB, 256, 0, stream>>>(dist_o, rel, x_o, rep_o, idx_o);
}